// Round 12
// baseline (60.494 us; speedup 1.0000x reference)
//
#include <hip/hip_runtime.h>
#include <hip/hip_bf16.h>
#include <stdint.h>

// KANLayer as GEMM: out[8192,512] = A[8192,1536]@W[1536,512] + bias, bf16 MFMA, fp32 accum.
//   Xpk[rb][g]: 1KB chunk, lane l = bf16 x[rb*16+(l&15)][g*32+(l>>4)*8..+7]   (8 MB)
//   Bpk[cb][g][p]: 1KB chunk, lane l = bf16 W[k][cb*16+(l&15)]                (1.5 MB)
// R12: MEASUREMENT ROUND. gemm K-loop repeated 3x in-kernel (acc=3S, epilogue x1/3,
// numerically exact to 1e-7) so the dispatch becomes visible in the rocprof top-5 with
// real MfmaUtil/VALUBusy/Occupancy/FETCH. Bias de-tailed: 8-way i-split partials
// bias_part[8][512] (no LDS, shallow chains), summed in the gemm epilogue.

static constexpr int ON_ = 512;

typedef __bf16 bf16x8 __attribute__((ext_vector_type(8)));
typedef float  f32x4  __attribute__((ext_vector_type(4)));

__device__ __forceinline__ unsigned int f2bf(float f) {
    unsigned int u = __float_as_uint(f);
    return ((u + 0x7FFFu + ((u >> 16) & 1u)) >> 16);   // RNE bf16, finite inputs
}

// ---- pack: blocks [0,512) x->Xpk via LDS ; [512,640) B->Bpk ; [640,656) bias partials
__global__ __launch_bounds__(256) void pack_all(const float* __restrict__ x,
                                                const float* __restrict__ edge_w,
                                                const float* __restrict__ comb_w,
                                                const float* __restrict__ edge_b,
                                                uint4* __restrict__ Xpk,
                                                uint4* __restrict__ Bpk,
                                                float* __restrict__ bias_part) {
    __shared__ float xs[16 * 516];     // 16 rows, pitch 516 f32 -> even LDS banks
    const int d = blockIdx.x;
    const int t = threadIdx.x;
    if (d < 512) {
        // rb via the gemm's bijective XCD swizzle: XCD c packs rb in [c*64,(c+1)*64)
        const int rb = (d & 7) * 64 + (d >> 3);
        const float* xb = x + (size_t)rb * 16 * 512;
#pragma unroll
        for (int it = 0; it < 8; ++it) {
            int e   = it * 1024 + t * 4;
            int row = e >> 9, col = e & 511;
            *(float4*)(xs + row * 516 + col) = *(const float4*)(xb + e);
        }
        __syncthreads();
        const int l = t & 63, wv = t >> 6;
        const float* src0 = xs + (l & 15) * 516 + ((l >> 4) << 3);
#pragma unroll
        for (int s = 0; s < 4; ++s) {
            const int g = wv * 4 + s;
            const float* src = src0 + g * 32;
            float4 v0 = *(const float4*)(src);
            float4 v1 = *(const float4*)(src + 4);
            uint4 o;
            o.x = f2bf(v0.x) | (f2bf(v0.y) << 16);
            o.y = f2bf(v0.z) | (f2bf(v0.w) << 16);
            o.z = f2bf(v1.x) | (f2bf(v1.y) << 16);
            o.w = f2bf(v1.z) | (f2bf(v1.w) << 16);
            Xpk[((size_t)rb * 16 + g) * 64 + l] = o;
        }
    } else if (d < 640) {
        int id = (d - 512) * 256 + t;
        int l  = id & 63;
        int u  = id >> 6;              // 0..511
        int g  = u & 15;
        int cb = u >> 4;               // 0..31
        int o  = cb * 16 + (l & 15);
        int i0 = g * 32 + ((l >> 4) << 3);
        unsigned int w[3][4];
#pragma unroll
        for (int j = 0; j < 4; ++j) {
            int ia = i0 + 2 * j, ic = ia + 1;
            float ca = comb_w[(size_t)ia * ON_ + o];
            float cc = comb_w[(size_t)ic * ON_ + o];
            const float* ea = edge_w + ((size_t)ia * ON_ + o) * 3;
            const float* ec = edge_w + ((size_t)ic * ON_ + o) * 3;
#pragma unroll
            for (int p = 0; p < 3; ++p)
                w[p][j] = f2bf(ea[p] * ca) | (f2bf(ec[p] * cc) << 16);
        }
        size_t base = ((size_t)cb * 48 + g * 3) * 64 + l;
        Bpk[base]       = make_uint4(w[0][0], w[0][1], w[0][2], w[0][3]);
        Bpk[base + 64]  = make_uint4(w[1][0], w[1][1], w[1][2], w[1][3]);
        Bpk[base + 128] = make_uint4(w[2][0], w[2][1], w[2][2], w[2][3]);
    } else {
        // bias partials: 16 blocks x 256 thr; seg s=ih*4+iseg covers 64 i's; no LDS, no tail
        const int b  = d - 640;          // 0..15
        const int og = b >> 1, ih = b & 1;
        const int o  = og * 64 + (t & 63);
        const int s  = ih * 4 + (t >> 6);  // 0..7
        const int i0 = s * 64;
        float acc = 0.f;
#pragma unroll 8
        for (int i = i0; i < i0 + 64; ++i)
            acc += comb_w[(size_t)i * ON_ + o] * edge_b[(size_t)i * ON_ + o];
        bias_part[s * ON_ + o] = acc;
    }
}

// one 16-row strip: a^1,a^2,a^3 MFMAs into acc[MI][0..1]; temps die at end of strip
#define STRIP(Am, MI, BP0, BP1, BP2, BQ0, BQ1, BQ2) do {                                   \
    bf16x8 a1_ = __builtin_bit_cast(bf16x8, Am);                                           \
    acc[MI][0] = __builtin_amdgcn_mfma_f32_16x16x32_bf16(a1_, __builtin_bit_cast(bf16x8, BP0), acc[MI][0], 0, 0, 0); \
    acc[MI][1] = __builtin_amdgcn_mfma_f32_16x16x32_bf16(a1_, __builtin_bit_cast(bf16x8, BQ0), acc[MI][1], 0, 0, 0); \
    float e0_ = __uint_as_float((Am).x << 16), e1_ = __uint_as_float((Am).x & 0xffff0000u); \
    float e2_ = __uint_as_float((Am).y << 16), e3_ = __uint_as_float((Am).y & 0xffff0000u); \
    float e4_ = __uint_as_float((Am).z << 16), e5_ = __uint_as_float((Am).z & 0xffff0000u); \
    float e6_ = __uint_as_float((Am).w << 16), e7_ = __uint_as_float((Am).w & 0xffff0000u); \
    float q0_ = e0_*e0_, q1_ = e1_*e1_, q2_ = e2_*e2_, q3_ = e3_*e3_;                      \
    float q4_ = e4_*e4_, q5_ = e5_*e5_, q6_ = e6_*e6_, q7_ = e7_*e7_;                      \
    bf16x8 s_ = (bf16x8){ (__bf16)q0_, (__bf16)q1_, (__bf16)q2_, (__bf16)q3_,              \
                          (__bf16)q4_, (__bf16)q5_, (__bf16)q6_, (__bf16)q7_ };            \
    acc[MI][0] = __builtin_amdgcn_mfma_f32_16x16x32_bf16(s_, __builtin_bit_cast(bf16x8, BP1), acc[MI][0], 0, 0, 0); \
    acc[MI][1] = __builtin_amdgcn_mfma_f32_16x16x32_bf16(s_, __builtin_bit_cast(bf16x8, BQ1), acc[MI][1], 0, 0, 0); \
    bf16x8 c_ = (bf16x8){ (__bf16)(q0_*e0_), (__bf16)(q1_*e1_), (__bf16)(q2_*e2_), (__bf16)(q3_*e3_), \
                          (__bf16)(q4_*e4_), (__bf16)(q5_*e5_), (__bf16)(q6_*e6_), (__bf16)(q7_*e7_) }; \
    acc[MI][0] = __builtin_amdgcn_mfma_f32_16x16x32_bf16(c_, __builtin_bit_cast(bf16x8, BP2), acc[MI][0], 0, 0, 0); \
    acc[MI][1] = __builtin_amdgcn_mfma_f32_16x16x32_bf16(c_, __builtin_bit_cast(bf16x8, BQ2), acc[MI][1], 0, 0, 0); \
} while (0)

#define COMP10(A0, A1, A2, A3, B0, B1, B2, B3, B4, B5) do {                                \
    STRIP(A0, 0, B0, B1, B2, B3, B4, B5);                                                  \
    STRIP(A1, 1, B0, B1, B2, B3, B4, B5);                                                  \
    STRIP(A2, 2, B0, B1, B2, B3, B4, B5);                                                  \
    STRIP(A3, 3, B0, B1, B2, B3, B4, B5);                                                  \
} while (0)

#define LOADG10(A0, A1, A2, A3, B0, B1, B2, B3, B4, B5) do {                               \
    A0 = *(const uint4*)(pa0); A1 = *(const uint4*)(pa1);                                  \
    A2 = *(const uint4*)(pa2); A3 = *(const uint4*)(pa3);                                  \
    B0 = *(const uint4*)(pb0);        B1 = *(const uint4*)(pb0 + 1024);                    \
    B2 = *(const uint4*)(pb0 + 2048); B3 = *(const uint4*)(pb1);                           \
    B4 = *(const uint4*)(pb1 + 1024); B5 = *(const uint4*)(pb1 + 2048);                    \
    pa0 += 1024; pa1 += 1024; pa2 += 1024; pa3 += 1024;                                    \
    pb0 += 3072; pb1 += 3072;                                                              \
} while (0)

#define WAITV(N) asm volatile("s_waitcnt vmcnt(" #N ")" ::: "memory")

// GEMM: tile 128x64, 4 waves 2x2 (wr,wc), wave-tile 64x32. 512 blocks. No LDS/barriers.
// DIAGNOSTIC: K-loop run 3x (acc = 3S), epilogue scales by 1/3 — visible in rocprof top-5.
__global__ __launch_bounds__(256, 2) void gemm_fused(const char* __restrict__ Xpk,
                                                     const char* __restrict__ Bpk,
                                                     const float* __restrict__ bias_part,
                                                     float* __restrict__ out) {
    const int tid = threadIdx.x;
    const int l   = tid & 63;
    const int wid = tid >> 6;
    const int wr  = wid >> 1, wc = wid & 1;

    // bijective XCD swizzle (512 % 8 == 0)
    int d  = blockIdx.x;
    int w  = (d & 7) * 64 + (d >> 3);
    int bx = w >> 3, by = w & 7;

    f32x4 acc[4][2] = {};

#pragma unroll 1
    for (int rep = 0; rep < 3; ++rep) {
        const char* pa0 = Xpk + ((size_t)(bx * 8 + wr * 4) * 16) * 1024 + (l << 4);
        const char* pa1 = pa0 + 16 * 1024;
        const char* pa2 = pa0 + 32 * 1024;
        const char* pa3 = pa0 + 48 * 1024;
        const char* pb0 = Bpk + ((size_t)(by * 4 + wc * 2) * 48) * 1024 + (l << 4);
        const char* pb1 = pb0 + 48 * 1024;

        uint4 uA0, uA1, uA2, uA3, uB0, uB1, uB2, uB3, uB4, uB5;   // ping
        uint4 vA0, vA1, vA2, vA3, vB0, vB1, vB2, vB3, vB4, vB5;   // pong

        LOADG10(uA0, uA1, uA2, uA3, uB0, uB1, uB2, uB3, uB4, uB5);   // group 0

#pragma unroll 1
        for (int it = 0; it < 8; ++it) {   // computes groups 2*it, 2*it+1
            LOADG10(vA0, vA1, vA2, vA3, vB0, vB1, vB2, vB3, vB4, vB5);
            WAITV(10);
            COMP10(uA0, uA1, uA2, uA3, uB0, uB1, uB2, uB3, uB4, uB5);
            LOADG10(uA0, uA1, uA2, uA3, uB0, uB1, uB2, uB3, uB4, uB5);
            WAITV(10);
            COMP10(vA0, vA1, vA2, vA3, vB0, vB1, vB2, vB3, vB4, vB5);
        }
        WAITV(0);
    }

    // epilogue: C/D layout col=lane&15, row=(lane>>4)*4+reg; scale 1/3; bias from partials
    const float inv3 = 1.0f / 3.0f;
    int lr = l >> 4, lc = l & 15;
#pragma unroll
    for (int n = 0; n < 2; ++n) {
        int o = (by << 6) + (wc << 5) + (n << 4) + lc;
        float bv = 0.f;
#pragma unroll
        for (int k = 0; k < 8; ++k) bv += bias_part[k * ON_ + o];
#pragma unroll
        for (int m = 0; m < 4; ++m) {
            int r0 = (bx << 7) + (wr << 6) + (m << 4) + (lr << 2);
#pragma unroll
            for (int j = 0; j < 4; ++j)
                out[(size_t)(r0 + j) * ON_ + o] = acc[m][n][j] * inv3 + bv;
        }
    }
}

extern "C" void kernel_launch(void* const* d_in, const int* in_sizes, int n_in,
                              void* d_out, int out_size, void* d_ws, size_t ws_size,
                              hipStream_t stream) {
    const float* x      = (const float*)d_in[0];
    const float* edge_w = (const float*)d_in[1];
    const float* edge_b = (const float*)d_in[2];
    const float* comb_w = (const float*)d_in[3];
    float* out = (float*)d_out;

    char* ws = (char*)d_ws;
    char* Xpk        = ws;                               // 8192*512*2   = 8,388,608 B
    char* Bpk        = ws + 8388608;                     // 1536*512*2   = 1,572,864 B
    float* bias_part = (float*)(ws + 8388608 + 1572864); // 8*512*4      = 16,384 B

    hipLaunchKernelGGL(pack_all, dim3(512 + 128 + 16), dim3(256), 0, stream,
                       x, edge_w, comb_w, edge_b, (uint4*)Xpk, (uint4*)Bpk, bias_part);
    hipLaunchKernelGGL(gemm_fused, dim3(512), dim3(256), 0, stream, Xpk, Bpk, bias_part, out);
}

// Round 13
// 36.736 us; speedup vs baseline: 1.6467x; 1.6467x over previous
//
#include <hip/hip_runtime.h>
#include <hip/hip_bf16.h>
#include <stdint.h>

// KANLayer: out[8192,512] = sum_{i,p} x[b,i]^(p+1) * (edge_w[i,o,p]*comb_w[i,o]) + bias[o]
// R13: A-matrix handoff DELETED. The gemm reads x (stable input, warm across replays)
// directly, staging each 128x32 f32 sub-panel into LDS via global_load_lds (per-lane
// gather source, linear LDS dest), computing x^2,x^3 in VALU (measured affordable,
// R12: VALUBusy 46%). Only W (1.5 MB Bpk) + bias partials are pre-packed.
//
// LDS A layout (per buf, 16KB): rb-region rb*2048; fragment piece (lane l', half h)
// lives at 16B-slot (l'&15) + 16*h + 32*(l'>>4)  [slot index within region].
//   - read:  lane l, addrs ((l&15)+(l>>4)*32)*16 and +256  -> slots 0..15 mod 32 per
//     16-lane group = conflict-free ds_read_b128.
//   - stage: instr (rb,q), lane l writes slot q*64+l (linear, required by gld_lds);
//     source chosen as the inverse map: row=(l&15), col = g*32+(q*2+(l>>5))*8+((l>>4)&1)*4
//     (verified: slot s=q*64+l -> l'=(s>>5)*16+(s&15), h=(s>>4)&1 matches read).
// B region (12KB): Bpk chunks are already fragment-major; stage linear, read at l*16.
//
// Race analysis (2 bufs, stage-ahead-1, TWO raw s_barriers/group): iter g issues
// STAGE(g+1)->buf^1 (disjoint from compute buf), WAITV(7) drains own stage(g),
// barrier#1 -> buf(g) complete for all; COMPUTE(g); barrier#2 -> all waves done
// reading buf(g) BEFORE iter g+1 issues STAGE(g+2) into it.

static constexpr int ON_ = 512;

typedef __bf16 bf16x8 __attribute__((ext_vector_type(8)));
typedef float  f32x4  __attribute__((ext_vector_type(4)));

__device__ __forceinline__ unsigned int f2bf(float f) {
    unsigned int u = __float_as_uint(f);
    return ((u + 0x7FFFu + ((u >> 16) & 1u)) >> 16);   // RNE bf16, finite inputs
}

__device__ __forceinline__ void gld_lds16(const void* g, void* l) {
    __builtin_amdgcn_global_load_lds(
        (const __attribute__((address_space(1))) unsigned int*)(uintptr_t)g,
        (__attribute__((address_space(3))) unsigned int*)(unsigned int)(uintptr_t)l,
        16, 0, 0);
}

// ---- pack: blocks [0,128) B->Bpk ; [128,144) bias partials (8 x 512)
__global__ __launch_bounds__(256) void pack_bw(const float* __restrict__ edge_w,
                                               const float* __restrict__ comb_w,
                                               const float* __restrict__ edge_b,
                                               uint4* __restrict__ Bpk,
                                               float* __restrict__ bias_part) {
    const int d = blockIdx.x;
    const int t = threadIdx.x;
    if (d < 128) {
        int id = d * 256 + t;
        int l  = id & 63;
        int u  = id >> 6;              // 0..511
        int g  = u & 15;
        int cb = u >> 4;               // 0..31
        int o  = cb * 16 + (l & 15);
        int i0 = g * 32 + ((l >> 4) << 3);
        unsigned int w[3][4];
#pragma unroll
        for (int j = 0; j < 4; ++j) {
            int ia = i0 + 2 * j, ic = ia + 1;
            float ca = comb_w[(size_t)ia * ON_ + o];
            float cc = comb_w[(size_t)ic * ON_ + o];
            const float* ea = edge_w + ((size_t)ia * ON_ + o) * 3;
            const float* ec = edge_w + ((size_t)ic * ON_ + o) * 3;
#pragma unroll
            for (int p = 0; p < 3; ++p)
                w[p][j] = f2bf(ea[p] * ca) | (f2bf(ec[p] * cc) << 16);
        }
        size_t base = ((size_t)cb * 48 + g * 3) * 64 + l;
        Bpk[base]       = make_uint4(w[0][0], w[0][1], w[0][2], w[0][3]);
        Bpk[base + 64]  = make_uint4(w[1][0], w[1][1], w[1][2], w[1][3]);
        Bpk[base + 128] = make_uint4(w[2][0], w[2][1], w[2][2], w[2][3]);
    } else {
        const int b  = d - 128;            // 0..15
        const int og = b >> 1, ih = b & 1;
        const int o  = og * 64 + (t & 63);
        const int s  = ih * 4 + (t >> 6);  // 0..7
        const int i0 = s * 64;
        float acc = 0.f;
#pragma unroll 8
        for (int i = i0; i < i0 + 64; ++i)
            acc += comb_w[(size_t)i * ON_ + o] * edge_b[(size_t)i * ON_ + o];
        bias_part[s * ON_ + o] = acc;
    }
}

#define WAITV(N) asm volatile("s_waitcnt vmcnt(" #N ")" ::: "memory")

#define MFMA(AF, BF, MI, NI) \
    acc[MI][NI] = __builtin_amdgcn_mfma_f32_16x16x32_bf16(AF, BF, acc[MI][NI], 0, 0, 0)

// one 16-row strip from f32 LDS fragments: a^1,a^2,a^3 into acc[M][0..1]
#define STRIPF(M) do {                                                                     \
    const char* ap_ = Ap + (M) * 2048;                                                     \
    float4 f0_ = *(const float4*)(ap_);                                                    \
    float4 f1_ = *(const float4*)(ap_ + 256);                                              \
    bf16x8 a1_ = (bf16x8){ (__bf16)f0_.x, (__bf16)f0_.y, (__bf16)f0_.z, (__bf16)f0_.w,     \
                           (__bf16)f1_.x, (__bf16)f1_.y, (__bf16)f1_.z, (__bf16)f1_.w };   \
    MFMA(a1_, B00, M, 0); MFMA(a1_, B10, M, 1);                                            \
    float q0_ = f0_.x * f0_.x, q1_ = f0_.y * f0_.y, q2_ = f0_.z * f0_.z, q3_ = f0_.w * f0_.w; \
    float q4_ = f1_.x * f1_.x, q5_ = f1_.y * f1_.y, q6_ = f1_.z * f1_.z, q7_ = f1_.w * f1_.w; \
    bf16x8 a2_ = (bf16x8){ (__bf16)q0_, (__bf16)q1_, (__bf16)q2_, (__bf16)q3_,             \
                           (__bf16)q4_, (__bf16)q5_, (__bf16)q6_, (__bf16)q7_ };           \
    MFMA(a2_, B01, M, 0); MFMA(a2_, B11, M, 1);                                            \
    bf16x8 a3_ = (bf16x8){ (__bf16)(q0_*f0_.x), (__bf16)(q1_*f0_.y), (__bf16)(q2_*f0_.z), (__bf16)(q3_*f0_.w), \
                           (__bf16)(q4_*f1_.x), (__bf16)(q5_*f1_.y), (__bf16)(q6_*f1_.z), (__bf16)(q7_*f1_.w) }; \
    MFMA(a3_, B02, M, 0); MFMA(a3_, B12, M, 1);                                            \
} while (0)

// stage group G into LDS at buf offset SO: 4 A gathers + 3 B chunks = 7 VMEM/wave
#define STAGE(G, SO) do {                                                                  \
    gld_lds16(sA0 + (size_t)(G) * 32,   L + (SO) + dA0);                                   \
    gld_lds16(sA1 + (size_t)(G) * 32,   L + (SO) + dA1);                                   \
    gld_lds16(sA2 + (size_t)(G) * 32,   L + (SO) + dA2);                                   \
    gld_lds16(sA3 + (size_t)(G) * 32,   L + (SO) + dA3);                                   \
    gld_lds16(sB0 + (size_t)(G) * 3072, L + (SO) + dB0);                                   \
    gld_lds16(sB1 + (size_t)(G) * 3072, L + (SO) + dB1);                                   \
    gld_lds16(sB2 + (size_t)(G) * 3072, L + (SO) + dB2);                                   \
} while (0)

// read 6 B frags once per group, then 4 strips
#define COMPUTE(CO) do {                                                                   \
    const char* Bw = L + (CO) + 16384 + wc * 6144 + (l << 4);                              \
    bf16x8 B00 = *(const bf16x8*)(Bw);                                                     \
    bf16x8 B01 = *(const bf16x8*)(Bw + 1024);                                              \
    bf16x8 B02 = *(const bf16x8*)(Bw + 2048);                                              \
    bf16x8 B10 = *(const bf16x8*)(Bw + 3072);                                              \
    bf16x8 B11 = *(const bf16x8*)(Bw + 4096);                                              \
    bf16x8 B12 = *(const bf16x8*)(Bw + 5120);                                              \
    const char* Ap = L + (CO) + (wr * 4) * 2048 + aoff;                                    \
    STRIPF(0); STRIPF(1); STRIPF(2); STRIPF(3);                                            \
} while (0)

// GEMM: tile 128x64, 4 waves 2x2 (wr,wc), wave-tile 64x32. 512 blocks, 56KB LDS x2buf.
__global__ __launch_bounds__(256, 2) void gemm_fused(const float* __restrict__ x,
                                                     const char* __restrict__ Bpk,
                                                     const float* __restrict__ bias_part,
                                                     float* __restrict__ out) {
    __shared__ char lds[2 * 28672];    // per buf: A 8x2KB @0, B 12x1KB @16384
    char* L = (char*)lds;
    const int tid = threadIdx.x;
    const int l   = tid & 63;
    const int wv  = tid >> 6;
    const int wr  = wv >> 1, wc = wv & 1;

    // bijective XCD swizzle (512 % 8 == 0): x panel shared by the 8 by-blocks of one bx,
    // all on the same XCD (d&7 = w>>6 identical for by=0..7) -> 7/8 of x reads are L2 hits.
    const int d  = blockIdx.x;
    const int w  = (d & 7) * 64 + (d >> 3);
    const int bx = w >> 3, by = w & 7;

    // A staging sources: instr (rb = wv*2 + (a>>1), q = a&1), lane l supplies
    // row (l&15) of rb, cols g*32 + (q*2+(l>>5))*8 + ((l>>4)&1)*4  (16B)
    const int rlo = l & 15, colq = l >> 5, half = (l >> 4) & 1;
    const float* xb0 = x + (size_t)(bx * 128 + (wv * 2)     * 16 + rlo) * 512 + colq * 8 + half * 4;
    const float* xb1 = x + (size_t)(bx * 128 + (wv * 2 + 1) * 16 + rlo) * 512 + colq * 8 + half * 4;
    const float* sA0 = xb0;          // q=0
    const float* sA1 = xb0 + 16;     // q=1 -> +2*8 cols
    const float* sA2 = xb1;
    const float* sA3 = xb1 + 16;
    const int dA0 = (wv * 2) * 2048, dA1 = dA0 + 1024;
    const int dA2 = (wv * 2 + 1) * 2048, dA3 = dA2 + 1024;

    // B staging: wave stages chunks j = wv*3 .. wv*3+2 (j = cbl*3+p)
    const int j0 = wv * 3, j1 = j0 + 1, j2 = j0 + 2;
    const char* sB0 = Bpk + ((size_t)((by * 4 + j0 / 3) * 48) + (j0 % 3)) * 1024 + (l << 4);
    const char* sB1 = Bpk + ((size_t)((by * 4 + j1 / 3) * 48) + (j1 % 3)) * 1024 + (l << 4);
    const char* sB2 = Bpk + ((size_t)((by * 4 + j2 / 3) * 48) + (j2 % 3)) * 1024 + (l << 4);
    const int dB0 = 16384 + j0 * 1024, dB1 = 16384 + j1 * 1024, dB2 = 16384 + j2 * 1024;

    const int aoff = ((l & 15) + (l >> 4) * 32) << 4;   // conflict-free fragment slot

    f32x4 acc[4][2] = {};

    STAGE(0, 0);
#pragma unroll 1
    for (int g = 0; g < 15; ++g) {
        const int so = ((g + 1) & 1) * 28672;
        const int co = (g & 1) * 28672;
        STAGE(g + 1, so);
        WAITV(7);                          // own stage(g) drained; stage(g+1) in flight
        __builtin_amdgcn_s_barrier();      // buf(g) complete for all waves
        COMPUTE(co);
        __builtin_amdgcn_s_barrier();      // all done reading buf(g) before overwrite
    }
    WAITV(0);
    __builtin_amdgcn_s_barrier();
    COMPUTE(28672);                        // g=15 -> buf 1

    // epilogue: C/D layout col=lane&15, row=(lane>>4)*4+reg; bias from 8 partials
    const int lr = l >> 4, lc = l & 15;
#pragma unroll
    for (int n = 0; n < 2; ++n) {
        int o = (by << 6) + (wc << 5) + (n << 4) + lc;
        float bv = 0.f;
#pragma unroll
        for (int k = 0; k < 8; ++k) bv += bias_part[k * ON_ + o];
#pragma unroll
        for (int m = 0; m < 4; ++m) {
            int r0 = (bx << 7) + (wr << 6) + (m << 4) + (lr << 2);
#pragma unroll
            for (int j = 0; j < 4; ++j)
                out[(size_t)(r0 + j) * ON_ + o] = acc[m][n][j] + bv;
        }
    }
}

extern "C" void kernel_launch(void* const* d_in, const int* in_sizes, int n_in,
                              void* d_out, int out_size, void* d_ws, size_t ws_size,
                              hipStream_t stream) {
    const float* x      = (const float*)d_in[0];
    const float* edge_w = (const float*)d_in[1];
    const float* edge_b = (const float*)d_in[2];
    const float* comb_w = (const float*)d_in[3];
    float* out = (float*)d_out;

    char* ws = (char*)d_ws;
    char* Bpk        = ws;                     // 1536*512*2 = 1,572,864 B
    float* bias_part = (float*)(ws + 1572864); // 8*512*4    = 16,384 B

    hipLaunchKernelGGL(pack_bw, dim3(144), dim3(256), 0, stream,
                       edge_w, comb_w, edge_b, (uint4*)Bpk, bias_part);
    hipLaunchKernelGGL(gemm_fused, dim3(512), dim3(256), 0, stream, x, Bpk, bias_part, out);
}

// Round 14
// 34.095 us; speedup vs baseline: 1.7743x; 1.0775x over previous
//
#include <hip/hip_runtime.h>
#include <hip/hip_bf16.h>
#include <stdint.h>

// KANLayer as GEMM: out[8192,512] = A[8192,1536]@W[1536,512] + bias, bf16 MFMA, fp32 accum.
//   Xpk[rb][g]: 1KB chunk, lane l = bf16 x[rb*16+(l&15)][g*32+(l>>4)*8..+7]   (8 MB)
//   Bpk[cb][g][p]: 1KB chunk, lane l = bf16 W[k][cb*16+(l&15)]                (1.5 MB)
// R14: R12 structure (all-register coalesced gemm, warm-11us path), single rep, with the
// pack->gemm handoff made CLEAN via __builtin_nontemporal_store on Xpk/Bpk/bias_part:
// no cross-XCD dirty-L2 snoop on the gemm's cold fetch (the measured 17us cold penalty).
// Pack x-section keeps the gemm's bijective XCD swizzle (producer XCD == consumer XCD).

static constexpr int ON_ = 512;

typedef __bf16 bf16x8 __attribute__((ext_vector_type(8)));
typedef float  f32x4  __attribute__((ext_vector_type(4)));

__device__ __forceinline__ unsigned int f2bf(float f) {
    unsigned int u = __float_as_uint(f);
    return ((u + 0x7FFFu + ((u >> 16) & 1u)) >> 16);   // RNE bf16, finite inputs
}

__device__ __forceinline__ void nt_store4(uint4* p, uint4 v) {
    __builtin_nontemporal_store(v.x, &p->x);
    __builtin_nontemporal_store(v.y, &p->y);
    __builtin_nontemporal_store(v.z, &p->z);
    __builtin_nontemporal_store(v.w, &p->w);
}

// ---- pack: blocks [0,512) x->Xpk via LDS ; [512,640) B->Bpk ; [640,656) bias partials
__global__ __launch_bounds__(256) void pack_all(const float* __restrict__ x,
                                                const float* __restrict__ edge_w,
                                                const float* __restrict__ comb_w,
                                                const float* __restrict__ edge_b,
                                                uint4* __restrict__ Xpk,
                                                uint4* __restrict__ Bpk,
                                                float* __restrict__ bias_part) {
    __shared__ float xs[16 * 516];     // 16 rows, pitch 516 f32 -> even LDS banks
    const int d = blockIdx.x;
    const int t = threadIdx.x;
    if (d < 512) {
        // rb via the gemm's bijective XCD swizzle: producer XCD == consumer XCD
        const int rb = (d & 7) * 64 + (d >> 3);
        const float* xb = x + (size_t)rb * 16 * 512;
#pragma unroll
        for (int it = 0; it < 8; ++it) {
            int e   = it * 1024 + t * 4;
            int row = e >> 9, col = e & 511;
            *(float4*)(xs + row * 516 + col) = *(const float4*)(xb + e);
        }
        __syncthreads();
        const int l = t & 63, wv = t >> 6;
        const float* src0 = xs + (l & 15) * 516 + ((l >> 4) << 3);
#pragma unroll
        for (int s = 0; s < 4; ++s) {
            const int g = wv * 4 + s;
            const float* src = src0 + g * 32;
            float4 v0 = *(const float4*)(src);
            float4 v1 = *(const float4*)(src + 4);
            uint4 o;
            o.x = f2bf(v0.x) | (f2bf(v0.y) << 16);
            o.y = f2bf(v0.z) | (f2bf(v0.w) << 16);
            o.z = f2bf(v1.x) | (f2bf(v1.y) << 16);
            o.w = f2bf(v1.z) | (f2bf(v1.w) << 16);
            nt_store4(&Xpk[((size_t)rb * 16 + g) * 64 + l], o);
        }
    } else if (d < 640) {
        int id = (d - 512) * 256 + t;
        int l  = id & 63;
        int u  = id >> 6;              // 0..511
        int g  = u & 15;
        int cb = u >> 4;               // 0..31
        int o  = cb * 16 + (l & 15);
        int i0 = g * 32 + ((l >> 4) << 3);
        unsigned int w[3][4];
#pragma unroll
        for (int j = 0; j < 4; ++j) {
            int ia = i0 + 2 * j, ic = ia + 1;
            float ca = comb_w[(size_t)ia * ON_ + o];
            float cc = comb_w[(size_t)ic * ON_ + o];
            const float* ea = edge_w + ((size_t)ia * ON_ + o) * 3;
            const float* ec = edge_w + ((size_t)ic * ON_ + o) * 3;
#pragma unroll
            for (int p = 0; p < 3; ++p)
                w[p][j] = f2bf(ea[p] * ca) | (f2bf(ec[p] * cc) << 16);
        }
        size_t base = ((size_t)cb * 48 + g * 3) * 64 + l;
        nt_store4(&Bpk[base],       make_uint4(w[0][0], w[0][1], w[0][2], w[0][3]));
        nt_store4(&Bpk[base + 64],  make_uint4(w[1][0], w[1][1], w[1][2], w[1][3]));
        nt_store4(&Bpk[base + 128], make_uint4(w[2][0], w[2][1], w[2][2], w[2][3]));
    } else {
        const int b  = d - 640;            // 0..15
        const int og = b >> 1, ih = b & 1;
        const int o  = og * 64 + (t & 63);
        const int s  = ih * 4 + (t >> 6);  // 0..7
        const int i0 = s * 64;
        float acc = 0.f;
#pragma unroll 8
        for (int i = i0; i < i0 + 64; ++i)
            acc += comb_w[(size_t)i * ON_ + o] * edge_b[(size_t)i * ON_ + o];
        __builtin_nontemporal_store(acc, &bias_part[s * ON_ + o]);
    }
}

// one 16-row strip: a^1,a^2,a^3 MFMAs into acc[MI][0..1]; temps die at end of strip
#define STRIP(Am, MI, BP0, BP1, BP2, BQ0, BQ1, BQ2) do {                                   \
    bf16x8 a1_ = __builtin_bit_cast(bf16x8, Am);                                           \
    acc[MI][0] = __builtin_amdgcn_mfma_f32_16x16x32_bf16(a1_, __builtin_bit_cast(bf16x8, BP0), acc[MI][0], 0, 0, 0); \
    acc[MI][1] = __builtin_amdgcn_mfma_f32_16x16x32_bf16(a1_, __builtin_bit_cast(bf16x8, BQ0), acc[MI][1], 0, 0, 0); \
    float e0_ = __uint_as_float((Am).x << 16), e1_ = __uint_as_float((Am).x & 0xffff0000u); \
    float e2_ = __uint_as_float((Am).y << 16), e3_ = __uint_as_float((Am).y & 0xffff0000u); \
    float e4_ = __uint_as_float((Am).z << 16), e5_ = __uint_as_float((Am).z & 0xffff0000u); \
    float e6_ = __uint_as_float((Am).w << 16), e7_ = __uint_as_float((Am).w & 0xffff0000u); \
    float q0_ = e0_*e0_, q1_ = e1_*e1_, q2_ = e2_*e2_, q3_ = e3_*e3_;                      \
    float q4_ = e4_*e4_, q5_ = e5_*e5_, q6_ = e6_*e6_, q7_ = e7_*e7_;                      \
    bf16x8 s_ = (bf16x8){ (__bf16)q0_, (__bf16)q1_, (__bf16)q2_, (__bf16)q3_,              \
                          (__bf16)q4_, (__bf16)q5_, (__bf16)q6_, (__bf16)q7_ };            \
    acc[MI][0] = __builtin_amdgcn_mfma_f32_16x16x32_bf16(s_, __builtin_bit_cast(bf16x8, BP1), acc[MI][0], 0, 0, 0); \
    acc[MI][1] = __builtin_amdgcn_mfma_f32_16x16x32_bf16(s_, __builtin_bit_cast(bf16x8, BQ1), acc[MI][1], 0, 0, 0); \
    bf16x8 c_ = (bf16x8){ (__bf16)(q0_*e0_), (__bf16)(q1_*e1_), (__bf16)(q2_*e2_), (__bf16)(q3_*e3_), \
                          (__bf16)(q4_*e4_), (__bf16)(q5_*e5_), (__bf16)(q6_*e6_), (__bf16)(q7_*e7_) }; \
    acc[MI][0] = __builtin_amdgcn_mfma_f32_16x16x32_bf16(c_, __builtin_bit_cast(bf16x8, BP2), acc[MI][0], 0, 0, 0); \
    acc[MI][1] = __builtin_amdgcn_mfma_f32_16x16x32_bf16(c_, __builtin_bit_cast(bf16x8, BQ2), acc[MI][1], 0, 0, 0); \
} while (0)

#define COMP10(A0, A1, A2, A3, B0, B1, B2, B3, B4, B5) do {                                \
    STRIP(A0, 0, B0, B1, B2, B3, B4, B5);                                                  \
    STRIP(A1, 1, B0, B1, B2, B3, B4, B5);                                                  \
    STRIP(A2, 2, B0, B1, B2, B3, B4, B5);                                                  \
    STRIP(A3, 3, B0, B1, B2, B3, B4, B5);                                                  \
} while (0)

#define LOADG10(A0, A1, A2, A3, B0, B1, B2, B3, B4, B5) do {                               \
    A0 = *(const uint4*)(pa0); A1 = *(const uint4*)(pa1);                                  \
    A2 = *(const uint4*)(pa2); A3 = *(const uint4*)(pa3);                                  \
    B0 = *(const uint4*)(pb0);        B1 = *(const uint4*)(pb0 + 1024);                    \
    B2 = *(const uint4*)(pb0 + 2048); B3 = *(const uint4*)(pb1);                           \
    B4 = *(const uint4*)(pb1 + 1024); B5 = *(const uint4*)(pb1 + 2048);                    \
    pa0 += 1024; pa1 += 1024; pa2 += 1024; pa3 += 1024;                                    \
    pb0 += 3072; pb1 += 3072;                                                              \
} while (0)

#define WAITV(N) asm volatile("s_waitcnt vmcnt(" #N ")" ::: "memory")

// GEMM: tile 128x64, 4 waves 2x2 (wr,wc), wave-tile 64x32. 512 blocks. No LDS/barriers.
__global__ __launch_bounds__(256, 2) void gemm_fused(const char* __restrict__ Xpk,
                                                     const char* __restrict__ Bpk,
                                                     const float* __restrict__ bias_part,
                                                     float* __restrict__ out) {
    const int tid = threadIdx.x;
    const int l   = tid & 63;
    const int wid = tid >> 6;
    const int wr  = wid >> 1, wc = wid & 1;

    // bijective XCD swizzle (512 % 8 == 0)
    int d  = blockIdx.x;
    int w  = (d & 7) * 64 + (d >> 3);
    int bx = w >> 3, by = w & 7;

    const char* pa0 = Xpk + ((size_t)(bx * 8 + wr * 4) * 16) * 1024 + (l << 4);
    const char* pa1 = pa0 + 16 * 1024;
    const char* pa2 = pa0 + 32 * 1024;
    const char* pa3 = pa0 + 48 * 1024;
    const char* pb0 = Bpk + ((size_t)(by * 4 + wc * 2) * 48) * 1024 + (l << 4);
    const char* pb1 = pb0 + 48 * 1024;

    f32x4 acc[4][2] = {};
    uint4 uA0, uA1, uA2, uA3, uB0, uB1, uB2, uB3, uB4, uB5;   // ping
    uint4 vA0, vA1, vA2, vA3, vB0, vB1, vB2, vB3, vB4, vB5;   // pong

    LOADG10(uA0, uA1, uA2, uA3, uB0, uB1, uB2, uB3, uB4, uB5);   // group 0

#pragma unroll 1
    for (int it = 0; it < 8; ++it) {   // computes groups 2*it, 2*it+1
        LOADG10(vA0, vA1, vA2, vA3, vB0, vB1, vB2, vB3, vB4, vB5);
        WAITV(10);
        COMP10(uA0, uA1, uA2, uA3, uB0, uB1, uB2, uB3, uB4, uB5);
        LOADG10(uA0, uA1, uA2, uA3, uB0, uB1, uB2, uB3, uB4, uB5);
        WAITV(10);
        COMP10(vA0, vA1, vA2, vA3, vB0, vB1, vB2, vB3, vB4, vB5);
    }

    // epilogue: C/D layout col=lane&15, row=(lane>>4)*4+reg; bias from 8 partials
    int lr = l >> 4, lc = l & 15;
#pragma unroll
    for (int n = 0; n < 2; ++n) {
        int o = (by << 6) + (wc << 5) + (n << 4) + lc;
        float bv = 0.f;
#pragma unroll
        for (int k = 0; k < 8; ++k) bv += bias_part[k * ON_ + o];
#pragma unroll
        for (int m = 0; m < 4; ++m) {
            int r0 = (bx << 7) + (wr << 6) + (m << 4) + (lr << 2);
#pragma unroll
            for (int j = 0; j < 4; ++j)
                out[(size_t)(r0 + j) * ON_ + o] = acc[m][n][j] + bv;
        }
    }
}

extern "C" void kernel_launch(void* const* d_in, const int* in_sizes, int n_in,
                              void* d_out, int out_size, void* d_ws, size_t ws_size,
                              hipStream_t stream) {
    const float* x      = (const float*)d_in[0];
    const float* edge_w = (const float*)d_in[1];
    const float* edge_b = (const float*)d_in[2];
    const float* comb_w = (const float*)d_in[3];
    float* out = (float*)d_out;

    char* ws = (char*)d_ws;
    char* Xpk        = ws;                               // 8192*512*2   = 8,388,608 B
    char* Bpk        = ws + 8388608;                     // 1536*512*2   = 1,572,864 B
    float* bias_part = (float*)(ws + 8388608 + 1572864); // 8*512*4      = 16,384 B

    hipLaunchKernelGGL(pack_all, dim3(512 + 128 + 16), dim3(256), 0, stream,
                       x, edge_w, comb_w, edge_b, (uint4*)Xpk, (uint4*)Bpk, bias_part);
    hipLaunchKernelGGL(gemm_fused, dim3(512), dim3(256), 0, stream, Xpk, Bpk, bias_part, out);
}